// Round 13
// baseline (315.151 us; speedup 1.0000x reference)
//
#include <hip/hip_runtime.h>

#define NN 100000
#define EE 1600000
#define NPAD 100032          // NN rounded up to 64-row MFMA tiles
#define NBKT 196             // ceil(NN/512) scatter buckets
#define CAP 9216             // bucket capacity (mean 8192, sigma 90 -> 11 sigma)
#define BN_EPS 1e-5f

using f32x4  = __attribute__((ext_vector_type(4))) float;
using f32x8  = __attribute__((ext_vector_type(8))) float;
using s16x8  = __attribute__((ext_vector_type(8))) short;
using u16x4  = __attribute__((ext_vector_type(4))) unsigned short;
using u16x8  = __attribute__((ext_vector_type(8))) unsigned short;
using bf16x8 = __attribute__((ext_vector_type(8))) __bf16;
typedef unsigned short ushort_t;

__device__ __forceinline__ float bf2f(ushort_t b) {
  union { unsigned u; float f; } x; x.u = ((unsigned)b) << 16; return x.f;
}
__device__ __forceinline__ ushort_t f2bf(float f) {
  union { float f; unsigned u; } x; x.f = f;
  unsigned r = x.u + 0x7fffu + ((x.u >> 16) & 1u);   // RN-even; no NaNs in pipeline
  return (ushort_t)(r >> 16);
}

// -------- merged k_bin + k_prep: blocks 0..781 bin (8 edges/thr),
//          782..7031 x->bf16, 7032..7044 W swizzle --------
__global__ __launch_bounds__(256) void k_binprep(
    const int* __restrict__ src, const int* __restrict__ dst,
    int* __restrict__ gbc, unsigned* __restrict__ ebuf,
    const float* __restrict__ x, ushort_t* __restrict__ hb,
    const float* __restrict__ W1s, const float* __restrict__ W2s,
    ushort_t* __restrict__ wf) {
  __shared__ int hist[NBKT];
  int b = blockIdx.x, t = threadIdx.x;
  if (b < 782) {
    for (int i = t; i < NBKT; i += 256) hist[i] = 0;
    __syncthreads();
    int base = b * 2048;
    int s[8], d[8];
#pragma unroll
    for (int j = 0; j < 8; j++) {
      int e = base + j * 256 + t;
      if (e < EE) { s[j] = src[e]; d[j] = dst[e]; atomicAdd(&hist[d[j] >> 9], 1); }
      else d[j] = -1;
    }
    __syncthreads();
    for (int i = t; i < NBKT; i += 256) {
      int c = hist[i];
      hist[i] = c ? atomicAdd(&gbc[i], c) : 0;   // reserve in-bucket run
    }
    __syncthreads();
#pragma unroll
    for (int j = 0; j < 8; j++) {
      if (d[j] >= 0) {
        int bkt = d[j] >> 9;
        int pos = atomicAdd(&hist[bkt], 1);
        if (pos < CAP)
          ebuf[(size_t)bkt * CAP + pos] = (unsigned)s[j] | ((unsigned)(d[j] & 511) << 17);
      }
    }
  } else if (b < 7032) {
    int i = (b - 782) * 256 + t;      // 4 elems of x each
    f32x4 v = *(const f32x4*)(x + (size_t)i * 4);
    u16x4 o;
#pragma unroll
    for (int m = 0; m < 4; m++) o[m] = f2bf(v[m]);
    *(u16x4*)(hb + (size_t)i * 4) = o;
  } else {
    int gid = (b - 7032) * 256 + t;
    if (gid >= 3072) return;          // 6 mats * 2u * 4t * 64 lanes
    int mat = gid >> 9, rem = gid & 511;
    int u = rem >> 8, tt = (rem >> 6) & 3, lane = rem & 63;
    const float* W = ((mat & 1) ? W2s : W1s) + (mat >> 1) * 4096;
    ushort_t* o = wf + gid * 8;
#pragma unroll
    for (int j = 0; j < 8; j++) {
      int k = u * 32 + (lane >> 4) * 8 + j;
      int n = tt * 16 + (lane & 15);
      o[j] = f2bf(W[k * 64 + n]);
    }
  }
}

// scan bucket counts -> ebase; rowptr[NN]=EE; zero BN stats
__global__ void k_bktscan(const int* __restrict__ gbc, int* __restrict__ ebase,
                          int* __restrict__ rowptr, float* __restrict__ stats) {
  __shared__ int sd[256];
  int t = threadIdx.x;
#pragma unroll
  for (int k = 0; k < 3; k++) stats[t + 256 * k] = 0.f;   // 768 floats
  int c = (t < NBKT) ? min(gbc[t], CAP) : 0;
  sd[t] = c; __syncthreads();
  for (int off = 1; off < 256; off <<= 1) {
    int x = 0;
    if (t >= off) x = sd[t - off];
    __syncthreads();
    sd[t] += x;
    __syncthreads();
  }
  if (t < NBKT) ebase[t] = sd[t] - c;          // exclusive
  if (t == NBKT - 1) rowptr[NN] = sd[t];       // == EE
}

// per bucket: LDS degree hist -> scan -> rowptr + fine scatter (1024 thr).
__global__ __launch_bounds__(1024) void k_fine(const unsigned* __restrict__ ebuf,
                                               const int* __restrict__ gbc,
                                               const int* __restrict__ ebase,
                                               int* __restrict__ rowptr,
                                               int* __restrict__ csr) {
  __shared__ int dcur[512];
  __shared__ int sd[256];
  int b = blockIdx.x, t = threadIdx.x;
  int cnt = min(gbc[b], CAP);
  int eb = ebase[b];
  const unsigned* eb_p = ebuf + (size_t)b * CAP;
  if (t < 512) dcur[t] = 0;
  __syncthreads();
  for (int e = t; e < cnt; e += 1024)
    atomicAdd(&dcur[(eb_p[e] >> 17) & 511], 1);
  __syncthreads();
  int a0 = 0, a1 = 0, ps = 0;
  if (t < 256) { a0 = dcur[2 * t]; a1 = dcur[2 * t + 1]; ps = a0 + a1; sd[t] = ps; }
  __syncthreads();
  for (int off = 1; off < 256; off <<= 1) {
    int x = 0;
    if (t < 256 && t >= off) x = sd[t - off];
    __syncthreads();
    if (t < 256) sd[t] += x;
    __syncthreads();
  }
  if (t < 256) {
    int g0 = eb + sd[t] - ps;                  // global csr start for local node 2t
    dcur[2 * t] = g0; dcur[2 * t + 1] = g0 + a0;
    int n = (b << 9) + 2 * t;
    if (n < NN) rowptr[n] = g0;
    if (n + 1 < NN) rowptr[n + 1] = g0 + a0;
  }
  __syncthreads();
  for (int e = t; e < cnt; e += 1024) {
    unsigned v = eb_p[e];
    int pos = atomicAdd(&dcur[(v >> 17) & 511], 1);
    csr[pos] = (int)(v & 0x1FFFFu);
  }
}

// ---------------- k_gat (v2: pair-pipelined, 32 lines in flight/wave) --------
// 256 thr = 32 groups of 8 lanes; group owns ONE node. Chunks of 8 edges are
// processed in PAIRS: both chunks' 16 indices load first, then all 16 row
// loads issue back-to-back (32 cache lines in flight — vmcnt ordering means
// interleaved consume would cap at 16). Counted waits retire chunk A's rows
// while B's stay in flight; next pair's indices land under ACC VALU. All
// chunks clamp-masked (weights in {0,1}, exact; OOB clamps to `last` -> valid
// L1-hot line). Named regs only; no LDS; no barriers.
#define GAT_LDIDX(P, EB)                                                      \
  P##0 = csr[min((EB), last)];     P##1 = csr[min((EB) + 1, last)];           \
  P##2 = csr[min((EB) + 2, last)]; P##3 = csr[min((EB) + 3, last)];           \
  P##4 = csr[min((EB) + 4, last)]; P##5 = csr[min((EB) + 5, last)];           \
  P##6 = csr[min((EB) + 6, last)]; P##7 = csr[min((EB) + 7, last)];

#define GAT_LDROW(R, P)                                                       \
  R##0 = *(const u16x8*)(hbase + (size_t)P##0 * 64);                          \
  R##1 = *(const u16x8*)(hbase + (size_t)P##1 * 64);                          \
  R##2 = *(const u16x8*)(hbase + (size_t)P##2 * 64);                          \
  R##3 = *(const u16x8*)(hbase + (size_t)P##3 * 64);                          \
  R##4 = *(const u16x8*)(hbase + (size_t)P##4 * 64);                          \
  R##5 = *(const u16x8*)(hbase + (size_t)P##5 * 64);                          \
  R##6 = *(const u16x8*)(hbase + (size_t)P##6 * 64);                          \
  R##7 = *(const u16x8*)(hbase + (size_t)P##7 * 64);

#define GAT_ACC(R, CNT) {                                                     \
  float w0 = ((CNT) > 0) ? 1.f : 0.f, w1 = ((CNT) > 1) ? 1.f : 0.f;           \
  float w2 = ((CNT) > 2) ? 1.f : 0.f, w3 = ((CNT) > 3) ? 1.f : 0.f;           \
  float w4 = ((CNT) > 4) ? 1.f : 0.f, w5 = ((CNT) > 5) ? 1.f : 0.f;           \
  float w6 = ((CNT) > 6) ? 1.f : 0.f, w7 = ((CNT) > 7) ? 1.f : 0.f;           \
  _Pragma("unroll") for (int m = 0; m < 8; m++) A[m] += w0 * bf2f(R##0[m]);   \
  _Pragma("unroll") for (int m = 0; m < 8; m++) A[m] += w1 * bf2f(R##1[m]);   \
  _Pragma("unroll") for (int m = 0; m < 8; m++) A[m] += w2 * bf2f(R##2[m]);   \
  _Pragma("unroll") for (int m = 0; m < 8; m++) A[m] += w3 * bf2f(R##3[m]);   \
  _Pragma("unroll") for (int m = 0; m < 8; m++) A[m] += w4 * bf2f(R##4[m]);   \
  _Pragma("unroll") for (int m = 0; m < 8; m++) A[m] += w5 * bf2f(R##5[m]);   \
  _Pragma("unroll") for (int m = 0; m < 8; m++) A[m] += w6 * bf2f(R##6[m]);   \
  _Pragma("unroll") for (int m = 0; m < 8; m++) A[m] += w7 * bf2f(R##7[m]); }

__global__ __launch_bounds__(256) void k_gat(
    const ushort_t* __restrict__ hb, const int* __restrict__ rowptr,
    const int* __restrict__ csr, ushort_t* __restrict__ aggb) {
  int tid = threadIdx.x;
  int grp = tid >> 3, fl = tid & 7;
  int node = blockIdx.x * 32 + grp;            // grid 3125*32 == NN exactly
  if (node >= NN) return;
  const ushort_t* hbase = hb + fl * 8;
  f32x8 A;
  {
    u16x8 sr = *(const u16x8*)(hbase + (size_t)node * 64);
#pragma unroll
    for (int m = 0; m < 8; m++) A[m] = bf2f(sr[m]);
  }
  int e = rowptr[node];
  int end = rowptr[node + 1];
  int rem = end - e;
  if (rem > 0) {
    int last = end - 1;
    int i0, i1, i2, i3, i4, i5, i6, i7;
    int j0, j1, j2, j3, j4, j5, j6, j7;
    u16x8 ra0, ra1, ra2, ra3, ra4, ra5, ra6, ra7;
    u16x8 rb0, rb1, rb2, rb3, rb4, rb5, rb6, rb7;
    // prologue: pair 0 (indices then 16 back-to-back row loads)
    GAT_LDIDX(i, e)
    GAT_LDIDX(j, e + 8)
    GAT_LDROW(ra, i)
    GAT_LDROW(rb, j)
    int cA = rem, cB = rem - 8;
    e += 16; rem -= 16;
    while (rem > 0) {
      GAT_LDIDX(i, e)                          // next pair's indices in flight
      GAT_LDIDX(j, e + 8)
      GAT_ACC(ra, cA)                          // retires A rows (B stays out)
      GAT_ACC(rb, cB)
      GAT_LDROW(ra, i)                         // idx landed under ACC VALU
      GAT_LDROW(rb, j)
      cA = rem; cB = rem - 8;
      e += 16; rem -= 16;
    }
    GAT_ACC(ra, cA)
    GAT_ACC(rb, cB)
  }
  u16x8 o;
#pragma unroll
  for (int m = 0; m < 8; m++) o[m] = f2bf(A[m]);
  *(u16x8*)(aggb + (size_t)node * 64 + fl * 8) = o;     // 128B/group coalesced
}

// ---------------- k_mlp1 (R9 proven): 8 tiles/block; stats in regs ----------
__global__ __launch_bounds__(256) void k_mlp1(
    const ushort_t* __restrict__ aggb, ushort_t* __restrict__ zb,
    const ushort_t* __restrict__ wfrag, const float* __restrict__ b1,
    float* __restrict__ stats) {
  __shared__ __align__(16) ushort_t sw[64 * 72];
  __shared__ __align__(16) ushort_t swb[64 * 72];
  __shared__ float lsum[64], lsq[64];
  int tid = threadIdx.x;
  if (tid < 64) lsum[tid] = 0.f;
  else if (tid < 128) lsq[tid - 64] = 0.f;
  int wv = tid >> 6, lane = tid & 63;
  int quad = lane >> 4, lo = lane & 15;
  int rr = tid >> 2, c0 = (tid & 3) * 16;      // staging coords

  s16x8 bfr[2][4];
#pragma unroll
  for (int u = 0; u < 2; u++)
#pragma unroll
    for (int t = 0; t < 4; t++)
      bfr[u][t] = *(const s16x8*)(wfrag + (size_t)((u * 4 + t) * 64 + lane) * 8);
  float bbv[4], s1a[4] = {0.f, 0.f, 0.f, 0.f}, s2a[4] = {0.f, 0.f, 0.f, 0.f};
#pragma unroll
  for (int t = 0; t < 4; t++) bbv[t] = b1[t * 16 + lo];

  for (int it = 0; it < 8; it++) {
    int row0 = blockIdx.x * 512 + it * 64;
    {   // stage tile into sw
      size_t grow = (size_t)row0 + rr;
      u16x8 v0 = {0, 0, 0, 0, 0, 0, 0, 0}, v1 = v0;
      if (grow < NN) {
        v0 = *(const u16x8*)(aggb + grow * 64 + c0);
        v1 = *(const u16x8*)(aggb + grow * 64 + c0 + 8);
      }
      *(u16x8*)(sw + rr * 72 + c0) = v0;
      *(u16x8*)(sw + rr * 72 + c0 + 8) = v1;
    }
    __syncthreads();                           // sw ready; prev zb reads of swb done
    f32x4 acc[4] = {};
#pragma unroll
    for (int u = 0; u < 2; u++) {
      bf16x8 af = *(const bf16x8*)(sw + (wv * 16 + lo) * 72 + u * 32 + quad * 8);
#pragma unroll
      for (int t = 0; t < 4; t++)
        acc[t] = __builtin_amdgcn_mfma_f32_16x16x32_bf16(
            af, __builtin_bit_cast(bf16x8, bfr[u][t]), acc[t], 0, 0, 0);
    }
#pragma unroll
    for (int t = 0; t < 4; t++) {
      int col = t * 16 + lo;
      float s1 = 0.f, s2 = 0.f;
#pragma unroll
      for (int r = 0; r < 4; r++) {
        int row = row0 + quad * 4 + r;
        if (row < NN) {
          float v = acc[t][r] + bbv[t];
          swb[(wv * 16 + quad * 4 + r) * 72 + col] = f2bf(v);
          s1 += v; s2 += v * v;
        }
      }
      s1a[t] += s1; s2a[t] += s2;
    }
    __syncthreads();                           // swb complete
    {
      size_t grow = (size_t)row0 + rr;
      if (grow < NN) {
        *(u16x8*)(zb + grow * 64 + c0)     = *(const u16x8*)(swb + rr * 72 + c0);
        *(u16x8*)(zb + grow * 64 + c0 + 8) = *(const u16x8*)(swb + rr * 72 + c0 + 8);
      }
    }
  }
  // per-block stats reduce: 16 LDS atomics/col, then 128 global atomics/block
#pragma unroll
  for (int t = 0; t < 4; t++) {
    int col = t * 16 + lo;
    atomicAdd(&lsum[col], s1a[t]);
    atomicAdd(&lsq[col], s2a[t]);
  }
  __syncthreads();
  if (tid < 64) {
    atomicAdd(&stats[tid], lsum[tid]);
    atomicAdd(&stats[64 + tid], lsq[tid]);
  }
}

// ---------------- k_mlp2 (R12 proven: blocked like mlp1) ----------------
__global__ __launch_bounds__(256) void k_mlp2(
    const ushort_t* __restrict__ zb, const float* __restrict__ stats,
    const float* __restrict__ gamma, const float* __restrict__ beta,
    const ushort_t* __restrict__ wfrag, const float* __restrict__ b2,
    ushort_t* __restrict__ hb, float* __restrict__ out,
    const float* __restrict__ Wd, const float* __restrict__ bd, int relu_out) {
  __shared__ __align__(16) ushort_t sw[64 * 72];
  __shared__ __align__(16) ushort_t swb[64 * 72];
  __shared__ __align__(16) float swf[64 * 68];     // f32 restage (decoder path)
  __shared__ float abn[64], cbn[64];
  int tid = threadIdx.x;
  if (tid < 64) {   // fused BN finalize (once per block)
    float inv = 1.f / (float)NN;
    float mu = stats[tid] * inv;
    float var = stats[64 + tid] * inv - mu * mu;
    float a = gamma[tid] * rsqrtf(var + BN_EPS);
    abn[tid] = a;
    cbn[tid] = beta[tid] - mu * a;
  }
  int wv = tid >> 6, lane = tid & 63;
  int quad = lane >> 4, lo = lane & 15;
  int rr = tid >> 2, c0 = (tid & 3) * 16;

  s16x8 bfr[2][4];
#pragma unroll
  for (int u = 0; u < 2; u++)
#pragma unroll
    for (int t = 0; t < 4; t++)
      bfr[u][t] = *(const s16x8*)(wfrag + (size_t)((u * 4 + t) * 64 + lane) * 8);
  float bbv[4];
#pragma unroll
  for (int t = 0; t < 4; t++) bbv[t] = b2[t * 16 + lo];
  float wd0[4], wd1[4], bd0 = 0.f, bd1 = 0.f;
  if (!relu_out) {
#pragma unroll
    for (int t = 0; t < 4; t++) {
      wd0[t] = Wd[(t * 16 + lo) * 2];
      wd1[t] = Wd[(t * 16 + lo) * 2 + 1];
    }
    bd0 = bd[0]; bd1 = bd[1];
  }
  __syncthreads();                             // abn/cbn ready

  float* outh = out + (size_t)NN * 2;
  for (int it = 0; it < 4; it++) {
    int row0 = blockIdx.x * 256 + it * 64;
    {   // stage: zb -> BN affine + ReLU -> bf16 tile in sw
      size_t grow = (size_t)row0 + rr;
      u16x8 zv0 = {0, 0, 0, 0, 0, 0, 0, 0}, zv1 = zv0;
      if (grow < NN) {
        zv0 = *(const u16x8*)(zb + grow * 64 + c0);
        zv1 = *(const u16x8*)(zb + grow * 64 + c0 + 8);
      }
      u16x8 o0, o1;
#pragma unroll
      for (int m = 0; m < 8; m++) {
        o0[m] = f2bf(fmaxf(bf2f(zv0[m]) * abn[c0 + m] + cbn[c0 + m], 0.f));
        o1[m] = f2bf(fmaxf(bf2f(zv1[m]) * abn[c0 + 8 + m] + cbn[c0 + 8 + m], 0.f));
      }
      *(u16x8*)(sw + rr * 72 + c0) = o0;
      *(u16x8*)(sw + rr * 72 + c0 + 8) = o1;
    }
    __syncthreads();                           // sw ready; prev-tile store reads done
    f32x4 acc[4] = {};
#pragma unroll
    for (int u = 0; u < 2; u++) {
      bf16x8 af = *(const bf16x8*)(sw + (wv * 16 + lo) * 72 + u * 32 + quad * 8);
#pragma unroll
      for (int t = 0; t < 4; t++)
        acc[t] = __builtin_amdgcn_mfma_f32_16x16x32_bf16(
            af, __builtin_bit_cast(bf16x8, bfr[u][t]), acc[t], 0, 0, 0);
    }
    if (relu_out) {
#pragma unroll
      for (int t = 0; t < 4; t++) {
        int col = t * 16 + lo;
#pragma unroll
        for (int r = 0; r < 4; r++)
          swb[(wv * 16 + quad * 4 + r) * 72 + col] =
              f2bf(fmaxf(acc[t][r] + bbv[t], 0.f));
      }
      __syncthreads();                         // swb complete
      size_t grow = (size_t)row0 + rr;
      if (grow < NN) {
        *(u16x8*)(hb + grow * 64 + c0)     = *(const u16x8*)(swb + rr * 72 + c0);
        *(u16x8*)(hb + grow * 64 + c0 + 8) = *(const u16x8*)(swb + rr * 72 + c0 + 8);
      }
    } else {
#pragma unroll
      for (int t = 0; t < 4; t++) {
        int col = t * 16 + lo;
#pragma unroll
        for (int r = 0; r < 4; r++)
          swf[(wv * 16 + quad * 4 + r) * 68 + col] = acc[t][r] + bbv[t];
      }
#pragma unroll
      for (int r = 0; r < 4; r++) {            // fused decoder (2 cols)
        float p0 = 0.f, p1 = 0.f;
#pragma unroll
        for (int t = 0; t < 4; t++) {
          float v = acc[t][r] + bbv[t];
          p0 += v * wd0[t]; p1 += v * wd1[t];
        }
#pragma unroll
        for (int o = 1; o < 16; o <<= 1) {     // reduce the quad's 16 lanes
          p0 += __shfl_xor(p0, o);
          p1 += __shfl_xor(p1, o);
        }
        int row = row0 + wv * 16 + quad * 4 + r;
        if (lo == 0 && row < NN) {
          out[(size_t)row * 2 + 0] = p0 + bd0;
          out[(size_t)row * 2 + 1] = p1 + bd1;
        }
      }
      __syncthreads();                         // swf complete
      size_t grow = (size_t)row0 + rr;
      if (grow < NN) {
#pragma unroll
        for (int h = 0; h < 4; h++)
          *(f32x4*)(outh + grow * 64 + c0 + h * 4) =
              *(const f32x4*)(swf + rr * 68 + c0 + h * 4);
      }
    }
  }
}

extern "C" void kernel_launch(void* const* d_in, const int* in_sizes, int n_in,
                              void* d_out, int out_size, void* d_ws, size_t ws_size,
                              hipStream_t stream) {
  (void)in_sizes; (void)n_in; (void)out_size; (void)ws_size;
  const float* x   = (const float*)d_in[0];
  const int*   ei  = (const int*)d_in[1];
  const float* W1s = (const float*)d_in[2];
  const float* b1s = (const float*)d_in[3];
  const float* gms = (const float*)d_in[4];
  const float* bts = (const float*)d_in[5];
  const float* W2s = (const float*)d_in[6];
  const float* b2s = (const float*)d_in[7];
  const float* Wd  = (const float*)d_in[8];
  const float* bd  = (const float*)d_in[9];
  float* out = (float*)d_out;
  const int* src = ei;
  const int* dst = ei + EE;

  char* w = (char*)d_ws;
  size_t off = 0;
  auto alloc = [&](size_t b) { char* p = w + off; off += (b + 255) & ~(size_t)255; return p; };
  ushort_t* zb     = (ushort_t*)alloc((size_t)NPAD * 64 * 2);   // 12.8 MB (ebuf aliases)
  ushort_t* aggb   = (ushort_t*)alloc((size_t)NPAD * 64 * 2);   // 12.8 MB bf16 aggregates
  ushort_t* hb16   = (ushort_t*)alloc((size_t)NPAD * 64 * 2);   // 12.8 MB bf16 rows
  int*      csr    = (int*)alloc((size_t)EE * 4);               // 6.4 MB
  int*      rowptr = (int*)alloc((size_t)(NN + 1) * 4);
  int*      gbc    = (int*)alloc((size_t)NBKT * 4);
  int*      ebase  = (int*)alloc((size_t)NBKT * 4);
  float*    stats  = (float*)alloc(768 * 4);                    // 3 x [sum|sq|spare]
  ushort_t* wf     = (ushort_t*)alloc((size_t)6 * 512 * 8 * 2); // swizzled W frags
  unsigned* ebuf   = (unsigned*)zb;  // 196*9216*4 = 7.2 MB, used pre-mlp only

  hipMemsetAsync(gbc, 0, (size_t)NBKT * 4, stream);
  k_binprep<<<7045, 256, 0, stream>>>(src, dst, gbc, ebuf, x, hb16, W1s, W2s, wf);
  k_bktscan<<<1, 256, 0, stream>>>(gbc, ebase, rowptr, stats);
  k_fine   <<<NBKT, 1024, 0, stream>>>(ebuf, gbc, ebase, rowptr, csr);

  int nblk2 = (NN + 255) / 256;     // 391
  for (int L = 0; L < 3; L++) {
    k_gat <<<(NN + 31) / 32, 256, 0, stream>>>(hb16, rowptr, csr, aggb);
    k_mlp1<<<NBKT, 256, 0, stream>>>(aggb, zb,
                                     wf + (size_t)(L * 2) * 4096,
                                     b1s + L * 64, stats + L * 256);
    k_mlp2<<<nblk2, 256, 0, stream>>>(zb, stats + L * 256,
                                      gms + L * 64, bts + L * 64,
                                      wf + (size_t)(L * 2 + 1) * 4096,
                                      b2s + L * 64, hb16, out, Wd, bd,
                                      (L < 2) ? 1 : 0);
  }
}